// Round 10
// baseline (1366.598 us; speedup 1.0000x reference)
//
#include <hip/hip_runtime.h>
#include <hip/hip_bf16.h>
#include <stdint.h>

using short8 = __attribute__((ext_vector_type(8))) short;
using uint4v = __attribute__((ext_vector_type(4))) unsigned int;
using f32x4  = __attribute__((ext_vector_type(4))) float;
using f32x16 = __attribute__((ext_vector_type(16))) float;

#define DEV __device__ __forceinline__

DEV float b2f(unsigned short u) {
  union { unsigned int i; float f; } v; v.i = ((unsigned int)u) << 16; return v.f;
}
DEV unsigned short f2b(float f) {
  union { float f; unsigned int i; } v; v.f = f;
  unsigned int x = v.i;
  return (unsigned short)((x + 0x7FFFu + ((x >> 16) & 1u)) >> 16);
}
DEV void g2lds16(const void* g, void* l) {
  __builtin_amdgcn_global_load_lds((const __attribute__((address_space(1))) void*)g,
                                   (__attribute__((address_space(3))) void*)l, 16, 0, 0);
}

// XCD-rectangular block mapping: XCD (wg&7) owns an rby x rbx rectangle of (by,bx).
DEV void xcd_rect_map(int wg, int nbx, int rby, int rbx, int& by, int& bx) {
  const int xcd_cols = nbx / rbx;
  const int xcd = wg & 7, local = wg >> 3;
  const int xr = xcd / xcd_cols, xc = xcd % xcd_cols;
  by = xr * rby + local / rbx;
  bx = xc * rbx + local % rbx;
}

enum { EPI_BF16 = 0, EPI_RESID_F32 = 1, EPI_BIAS_BF16 = 2, EPI_RESID_OUT = 3, EPI_SWIGLU = 4 };

// ---------------------------------------------------------------- GEMM 256x256, 32x32x16 MFMA, free-running
// 8 waves (2M x 4N), wave tile 128x64 = 4mi x 2ni of 32x32. 2 phases/tile (2 mi each, 16 MFMA,
// 4 indep acc chains). Only tile-boundary vmcnt(0)+barrier. LDS XOR-swizzled as before.
template<int EPI>
__global__ __launch_bounds__(512, 2)
void gemm_bt256(const unsigned short* __restrict__ A, const unsigned short* __restrict__ Bt,
                void* __restrict__ Cout, const void* __restrict__ extra,
                const void* __restrict__ extra2, int M, int N, int K, int rby, int rbx) {
  __shared__ __align__(16) unsigned short As[2][256 * 64];
  __shared__ __align__(16) unsigned short Bs[2][256 * 64];
  int by, bx;
  xcd_rect_map(blockIdx.x, N >> 8, rby, rbx, by, bx);
  const int m0 = by << 8, n0 = bx << 8;
  const int t = threadIdx.x;
  const int l = t & 63, wid = t >> 6;
  const int l31 = l & 31;
  const int hi8 = (l >> 5) << 3;     // k-subgroup offset (elements)
  const int wr = (wid >> 2) << 7;    // 0 or 128
  const int wc = (wid & 3) << 6;     // 0,64,128,192

  f32x16 acc[4][2];
#pragma unroll
  for (int i = 0; i < 4; ++i)
#pragma unroll
    for (int j = 0; j < 2; ++j)
#pragma unroll
      for (int r = 0; r < 16; ++r) acc[i][j][r] = 0.f;

  const int sr = t >> 3;                               // 0..63
  const int scSwz = ((t & 7) << 3) ^ ((sr & 7) << 3);  // pre-swizzled source column
  const unsigned short* Ag = A  + (size_t)(m0 + sr) * K + scSwz;
  const unsigned short* Bg = Bt + (size_t)(n0 + sr) * K + scSwz;
  const int nT = K >> 6;

  const unsigned short* AgNext = Ag + 64;
  const unsigned short* BgNext = Bg + 64;
  const size_t rowK64 = (size_t)64 * K;

  short8 af[2][4], bfr[2][4];

#define STAGE_A(buf)                                                  \
  {                                                                   \
    unsigned short* dst = &As[buf][t * 8];                            \
    _Pragma("unroll")                                                 \
    for (int ld = 0; ld < 4; ++ld)                                    \
      g2lds16(AgNext + (size_t)ld * rowK64, dst + ld * 4096);         \
  }
#define STAGE_B(buf)                                                  \
  {                                                                   \
    unsigned short* dst = &Bs[buf][t * 8];                            \
    _Pragma("unroll")                                                 \
    for (int ld = 0; ld < 4; ++ld)                                    \
      g2lds16(BgNext + (size_t)ld * rowK64, dst + ld * 4096);         \
  }
// read A-frags for mi pair (mi0, mi0+1): af[a][ks], row = wr + (mi0+a)*32 + l31, k = ks*16 + hi8
#define READ_A2(base, mi0)                                            \
  {                                                                   \
    _Pragma("unroll")                                                 \
    for (int a = 0; a < 2; ++a) {                                     \
      const int row = wr + ((mi0) + a) * 32 + l31;                    \
      const int ro = row << 6;                                        \
      const int sw = (row & 7) << 3;                                  \
      _Pragma("unroll")                                               \
      for (int ks = 0; ks < 4; ++ks)                                  \
        af[a][ks] = *(const short8*)((base) + ro + ((ks * 16 + hi8) ^ sw)); \
    }                                                                 \
  }
#define READ_B(base)                                                  \
  {                                                                   \
    _Pragma("unroll")                                                 \
    for (int ni = 0; ni < 2; ++ni) {                                  \
      const int row = wc + ni * 32 + l31;                             \
      const int ro = row << 6;                                        \
      const int sw = (row & 7) << 3;                                  \
      _Pragma("unroll")                                               \
      for (int ks = 0; ks < 4; ++ks)                                  \
        bfr[ni][ks] = *(const short8*)((base) + ro + ((ks * 16 + hi8) ^ sw)); \
    }                                                                 \
  }
// 16 MFMA: mi pair x 2 ni x 4 ks; ks-outer rotation -> 4 independent acc chains
#define MFMA_PH32(mi0)                                                \
  {                                                                   \
    _Pragma("unroll")                                                 \
    for (int ks = 0; ks < 4; ++ks)                                    \
      _Pragma("unroll")                                               \
      for (int a = 0; a < 2; ++a)                                     \
        _Pragma("unroll")                                             \
        for (int ni = 0; ni < 2; ++ni)                                \
          acc[(mi0) + a][ni] = __builtin_amdgcn_mfma_f32_32x32x16_bf16( \
              af[a][ks], bfr[ni][ks], acc[(mi0) + a][ni], 0, 0, 0);   \
  }

  // prologue: stage tile 0
  {
    unsigned short* dstA = &As[0][t * 8];
    unsigned short* dstB = &Bs[0][t * 8];
#pragma unroll
    for (int ld = 0; ld < 4; ++ld) {
      g2lds16(Ag + (size_t)ld * rowK64, dstA + ld * 4096);
      g2lds16(Bg + (size_t)ld * rowK64, dstB + ld * 4096);
    }
  }
  asm volatile("s_waitcnt vmcnt(0)\n\ts_barrier" ::: "memory");

  for (int tt = 0; tt < nT; ++tt) {
    const unsigned short* baseA = &As[tt & 1][0];
    const unsigned short* baseB = &Bs[tt & 1][0];
    const int nb = (tt + 1) & 1;
    const bool more = (tt + 1) < nT;
    // phase 0: mi 0,1
    if (more) STAGE_A(nb);
    READ_B(baseB);
    READ_A2(baseA, 0);
    asm volatile("s_waitcnt lgkmcnt(0)" ::: "memory");
    __builtin_amdgcn_sched_barrier(0);
    __builtin_amdgcn_s_setprio(1);
    MFMA_PH32(0);
    __builtin_amdgcn_s_setprio(0);
    // phase 1: mi 2,3
    if (more) STAGE_B(nb);
    READ_A2(baseA, 2);
    asm volatile("s_waitcnt lgkmcnt(0)" ::: "memory");
    __builtin_amdgcn_sched_barrier(0);
    __builtin_amdgcn_s_setprio(1);
    MFMA_PH32(2);
    __builtin_amdgcn_s_setprio(0);
    asm volatile("s_waitcnt vmcnt(0)\n\ts_barrier" ::: "memory");
    if (more) { AgNext += 64; BgNext += 64; }
  }
#undef STAGE_A
#undef STAGE_B
#undef READ_A2
#undef READ_B
#undef MFMA_PH32

  // epilogue: 32x32 C/D layout: col = lane&31, row = (reg&3) + 8*(reg>>2) + 4*(lane>>5)
  const int rbase = ((l >> 5) << 2);
#pragma unroll
  for (int mi = 0; mi < 4; ++mi) {
#pragma unroll
    for (int ni = 0; ni < 2; ++ni) {
      const int col = n0 + wc + ni * 32 + l31;
#pragma unroll
      for (int reg = 0; reg < 16; ++reg) {
        const int row = m0 + wr + mi * 32 + (reg & 3) + ((reg >> 2) << 3) + rbase;
        const size_t idx = (size_t)row * N + col;
        const float v = acc[mi][ni][reg];
        if constexpr (EPI == EPI_BF16) {
          ((unsigned short*)Cout)[idx] = f2b(v);
        } else if constexpr (EPI == EPI_RESID_F32) {
          ((float*)Cout)[idx] = v + ((const float*)extra)[idx];
        } else if constexpr (EPI == EPI_BIAS_BF16) {
          ((unsigned short*)Cout)[idx] = f2b(v + ((const float*)extra)[col]);
        } else if constexpr (EPI == EPI_SWIGLU) {
          const float g1v = b2f(((const unsigned short*)extra2)[idx]);
          const float v2 = v + ((const float*)extra)[col];
          ((unsigned short*)Cout)[idx] = f2b(g1v / (1.f + __expf(-g1v)) * v2);
        } else {
          ((float*)Cout)[idx] = v + ((const float*)extra)[idx];
        }
      }
    }
  }
}

// ---------------------------------------------------------------- GEMM 128x128 (m97 + T2 swizzle) for N=2048 GEMMs
template<int EPI>
__global__ __launch_bounds__(256)
void gemm_bt(const unsigned short* __restrict__ A, const unsigned short* __restrict__ Bt,
             void* __restrict__ Cout, const void* __restrict__ extra,
             int M, int N, int K, int rby, int rbx) {
  __shared__ __align__(16) unsigned short As[128 * 64];
  __shared__ __align__(16) unsigned short Bs[128 * 64];
  int by, bx;
  xcd_rect_map(blockIdx.x, N >> 7, rby, rbx, by, bx);
  const int m0 = by << 7, n0 = bx << 7;
  const int t = threadIdx.x;
  const int l = t & 63, w = t >> 6;
  const int lr = l & 15, lg = l >> 4;
  const int wr = (w >> 1) << 6, wc = (w & 1) << 6;

  f32x4 acc[4][4];
#pragma unroll
  for (int i = 0; i < 4; ++i)
#pragma unroll
    for (int j = 0; j < 4; ++j) acc[i][j] = (f32x4){0.f, 0.f, 0.f, 0.f};

  const int sr = t >> 3;
  const int skSwz = ((t & 7) << 3) ^ ((sr & 7) << 3);
  const unsigned short* Ag = A  + (size_t)(m0 + sr) * K + skSwz;
  const unsigned short* Bg = Bt + (size_t)(n0 + sr) * K + skSwz;
  unsigned short* Al = As + t * 8;
  unsigned short* Bl = Bs + t * 8;

  for (int kt = 0; kt < K; kt += 64) {
#pragma unroll
    for (int c = 0; c < 4; ++c) {
      g2lds16(Ag + (size_t)(c * 32) * K + kt, Al + c * 2048);
      g2lds16(Bg + (size_t)(c * 32) * K + kt, Bl + c * 2048);
    }
    __syncthreads();
#pragma unroll
    for (int ks = 0; ks < 2; ++ks) {
      short8 af[4], bfr[4];
#pragma unroll
      for (int mi = 0; mi < 4; ++mi) {
        const int row = wr + mi * 16 + lr;
        af[mi] = *(const short8*)(As + (row << 6) + (((ks * 32 + lg * 8)) ^ ((row & 7) << 3)));
      }
#pragma unroll
      for (int ni = 0; ni < 4; ++ni) {
        const int row = wc + ni * 16 + lr;
        bfr[ni] = *(const short8*)(Bs + (row << 6) + (((ks * 32 + lg * 8)) ^ ((row & 7) << 3)));
      }
#pragma unroll
      for (int mi = 0; mi < 4; ++mi)
#pragma unroll
        for (int ni = 0; ni < 4; ++ni)
          acc[mi][ni] = __builtin_amdgcn_mfma_f32_16x16x32_bf16(af[mi], bfr[ni], acc[mi][ni], 0, 0, 0);
    }
    __syncthreads();
  }

#pragma unroll
  for (int mi = 0; mi < 4; ++mi) {
#pragma unroll
    for (int ni = 0; ni < 4; ++ni) {
      const int col = n0 + wc + ni * 16 + lr;
#pragma unroll
      for (int j = 0; j < 4; ++j) {
        const int row = m0 + wr + mi * 16 + lg * 4 + j;
        const size_t idx = (size_t)row * N + col;
        const float v = acc[mi][ni][j];
        if constexpr (EPI == EPI_BF16) {
          ((unsigned short*)Cout)[idx] = f2b(v);
        } else if constexpr (EPI == EPI_RESID_F32) {
          ((float*)Cout)[idx] = v + ((const float*)extra)[idx];
        } else if constexpr (EPI == EPI_BIAS_BF16) {
          ((unsigned short*)Cout)[idx] = f2b(v + ((const float*)extra)[col]);
        } else {
          ((float*)Cout)[idx] = v + ((const float*)extra)[idx];
        }
      }
    }
  }
}

// ---------------------------------------------------------------- flash attention
__global__ __launch_bounds__(256)
void attn_fwd(const unsigned short* __restrict__ qkv, const unsigned short* __restrict__ vt,
              const float* __restrict__ mask, unsigned short* __restrict__ out) {
  __shared__ __align__(16) unsigned short Ks[64 * 128];
  __shared__ __align__(16) unsigned short Vs[128 * 64];
  __shared__ __align__(16) unsigned short Ps[4][16 * 64];
  const int b = blockIdx.z, hh = blockIdx.y;
  const int q0 = blockIdx.x << 6;
  const int t = threadIdx.x, l = t & 63, w = t >> 6;
  const int lr = l & 15, lg = l >> 4;
  const float scale = 0.08838834764831845f;

  short8 qf[4];
  {
    const unsigned short* qb = qkv + (size_t)(b * 2048 + q0 + w * 16 + lr) * 6144 + hh * 128;
#pragma unroll
    for (int ks = 0; ks < 4; ++ks) qf[ks] = *(const short8*)(qb + ks * 32 + lg * 8);
  }
  f32x4 acc_o[8];
#pragma unroll
  for (int i = 0; i < 8; ++i) acc_o[i] = (f32x4){0.f, 0.f, 0.f, 0.f};
  float m_r[4], l_r[4];
#pragma unroll
  for (int j = 0; j < 4; ++j) { m_r[j] = -1e30f; l_r[j] = 0.f; }

  const unsigned short* kb = qkv + (size_t)(b * 2048) * 6144 + 2048 + hh * 128;
  const unsigned short* vb = vt + (size_t)(b * 16 + hh) * 128 * 2048;
  const float* mb = mask + b * 2048;

  for (int kt = 0; kt < 2048; kt += 64) {
#pragma unroll
    for (int c = 0; c < 4; ++c) {
      const int e = (c * 256 + t) * 8;
      const int kr = e >> 7, kc = e & 127;
      g2lds16(kb + (size_t)(kt + kr) * 6144 + (kc ^ ((kr & 7) << 3)), Ks + e);
      const int vr = e >> 6, vc = e & 63;
      g2lds16(vb + (size_t)vr * 2048 + kt + (vc ^ ((vr & 7) << 3)), Vs + e);
    }
    __syncthreads();

    f32x4 sc[4];
#pragma unroll
    for (int nt = 0; nt < 4; ++nt) {
      f32x4 s = (f32x4){0.f, 0.f, 0.f, 0.f};
#pragma unroll
      for (int ks = 0; ks < 4; ++ks) {
        short8 kf = *(const short8*)(Ks + ((nt * 16 + lr) << 7) + ((ks * 32 + lg * 8) ^ ((lr & 7) << 3)));
        s = __builtin_amdgcn_mfma_f32_16x16x32_bf16(qf[ks], kf, s, 0, 0, 0);
      }
      sc[nt] = s;
    }
#pragma unroll
    for (int nt = 0; nt < 4; ++nt) {
      const float mv = mb[kt + nt * 16 + lr];
#pragma unroll
      for (int j = 0; j < 4; ++j) sc[nt][j] = sc[nt][j] * scale + mv;
    }
#pragma unroll
    for (int j = 0; j < 4; ++j) {
      float tm = fmaxf(fmaxf(sc[0][j], sc[1][j]), fmaxf(sc[2][j], sc[3][j]));
      tm = fmaxf(tm, __shfl_xor(tm, 1));
      tm = fmaxf(tm, __shfl_xor(tm, 2));
      tm = fmaxf(tm, __shfl_xor(tm, 4));
      tm = fmaxf(tm, __shfl_xor(tm, 8));
      const float mn = fmaxf(m_r[j], tm);
      const float corr = __expf(m_r[j] - mn);
      m_r[j] = mn;
      float ps = 0.f;
#pragma unroll
      for (int nt = 0; nt < 4; ++nt) {
        const float p = __expf(sc[nt][j] - mn);
        sc[nt][j] = p;
        ps += p;
      }
      ps += __shfl_xor(ps, 1);
      ps += __shfl_xor(ps, 2);
      ps += __shfl_xor(ps, 4);
      ps += __shfl_xor(ps, 8);
      l_r[j] = l_r[j] * corr + ps;
#pragma unroll
      for (int di = 0; di < 8; ++di) acc_o[di][j] *= corr;
    }
#pragma unroll
    for (int nt = 0; nt < 4; ++nt)
#pragma unroll
      for (int j = 0; j < 4; ++j) {
        const int q = lg * 4 + j;
        Ps[w][(q << 6) + ((nt * 16 + lr) ^ ((q & 7) << 3))] = f2b(sc[nt][j]);
      }
    asm volatile("s_waitcnt lgkmcnt(0)" ::: "memory");
#pragma unroll
    for (int ks2 = 0; ks2 < 2; ++ks2) {
      short8 pf = *(const short8*)(&Ps[w][(lr << 6) + ((ks2 * 32 + lg * 8) ^ ((lr & 7) << 3))]);
#pragma unroll
      for (int di = 0; di < 8; ++di) {
        short8 vf = *(const short8*)(Vs + ((di * 16 + lr) << 6) + ((ks2 * 32 + lg * 8) ^ ((lr & 7) << 3)));
        acc_o[di] = __builtin_amdgcn_mfma_f32_16x16x32_bf16(pf, vf, acc_o[di], 0, 0, 0);
      }
    }
    __syncthreads();
  }
#pragma unroll
  for (int di = 0; di < 8; ++di)
#pragma unroll
    for (int j = 0; j < 4; ++j) {
      const int q = q0 + w * 16 + lg * 4 + j;
      out[(size_t)(b * 2048 + q) * 2048 + hh * 128 + di * 16 + lr] = f2b(acc_o[di][j] / l_r[j]);
    }
}

// ---------------------------------------------------------------- RMSNorm (fp32 in, bf16 out, D=2048)
__global__ __launch_bounds__(256)
void rmsnorm_k(const float* __restrict__ in, const float* __restrict__ wgt,
               unsigned short* __restrict__ out) {
  __shared__ float red[4];
  const int row = blockIdx.x, t = threadIdx.x;
  const float4* rp = (const float4*)(in + (size_t)row * 2048 + t * 8);
  float4 a = rp[0], b = rp[1];
  float x[8] = {a.x, a.y, a.z, a.w, b.x, b.y, b.z, b.w};
  float s = 0.f;
#pragma unroll
  for (int i = 0; i < 8; ++i) s += x[i] * x[i];
#pragma unroll
  for (int m = 1; m < 64; m <<= 1) s += __shfl_xor(s, m);
  const int l = t & 63, w = t >> 6;
  if (l == 0) red[w] = s;
  __syncthreads();
  const float tot = red[0] + red[1] + red[2] + red[3];
  const float rr = rsqrtf(tot * (1.f / 2048.f) + 1e-5f);
  const float4* wp = (const float4*)(wgt + t * 8);
  float4 wa = wp[0], wb = wp[1];
  float ww[8] = {wa.x, wa.y, wa.z, wa.w, wb.x, wb.y, wb.z, wb.w};
  short8 o;
#pragma unroll
  for (int i = 0; i < 8; ++i) o[i] = (short)f2b(x[i] * rr * ww[i]);
  *(short8*)(out + (size_t)row * 2048 + t * 8) = o;
}

// ---------------------------------------------------------------- transpose + fp32->bf16 (pair-packed LDS)
__global__ __launch_bounds__(256)
void transpose2d(const float* __restrict__ in, unsigned short* __restrict__ out,
                 int R, int C) {
  __shared__ __align__(16) unsigned int tile2[64][36];
  const int r0 = blockIdx.y << 6, c0 = blockIdx.x << 6;
  const int t = threadIdx.x;
#pragma unroll
  for (int it = 0; it < 2; ++it) {
    const int p = it * 256 + t;
    const int r2 = p >> 4;
    const int c = (p & 15) << 2;
    const float* src = in + (size_t)(r0 + r2 * 2) * C + c0 + c;
    float4 va = *(const float4*)(src);
    float4 vb = *(const float4*)(src + C);
    tile2[c + 0][r2] = (unsigned int)f2b(va.x) | ((unsigned int)f2b(vb.x) << 16);
    tile2[c + 1][r2] = (unsigned int)f2b(va.y) | ((unsigned int)f2b(vb.y) << 16);
    tile2[c + 2][r2] = (unsigned int)f2b(va.z) | ((unsigned int)f2b(vb.z) << 16);
    tile2[c + 3][r2] = (unsigned int)f2b(va.w) | ((unsigned int)f2b(vb.w) << 16);
  }
  __syncthreads();
#pragma unroll
  for (int it = 0; it < 2; ++it) {
    const int u = it * 256 + t;
    const int rr = u >> 3;
    const int k8 = u & 7;
    uint4v v = *(const uint4v*)(&tile2[rr][k8 * 4]);
    short8 o;
#pragma unroll
    for (int j = 0; j < 4; ++j) {
      o[2 * j]     = (short)(v[j] & 0xFFFFu);
      o[2 * j + 1] = (short)(v[j] >> 16);
    }
    *(short8*)(out + (size_t)(c0 + rr) * R + r0 + k8 * 8) = o;
  }
}

// ---------------------------------------------------------------- V transpose
__global__ __launch_bounds__(256)
void transpose_v(const unsigned short* __restrict__ qkv, unsigned short* __restrict__ vt) {
  __shared__ __align__(16) unsigned short tile[64][72];
  const int s0 = blockIdx.x << 6, d0 = blockIdx.y << 6;
  const int z = blockIdx.z;
  const unsigned short* in = qkv + (size_t)((z >> 4) * 2048) * 6144 + 4096 + (z & 15) * 128;
  unsigned short* outp = vt + (size_t)z * 128 * 2048;
  const int t = threadIdx.x;
#pragma unroll
  for (int it = 0; it < 2; ++it) {
    const int e = (it * 256 + t) * 8;
    const int r = e >> 6, cc = e & 63;
    short8 v = *(const short8*)(in + (size_t)(s0 + r) * 6144 + d0 + cc);
#pragma unroll
    for (int i = 0; i < 8; ++i) tile[cc + i][r] = (unsigned short)v[i];
  }
  __syncthreads();
#pragma unroll
  for (int it = 0; it < 2; ++it) {
    const int e = (it * 256 + t) * 8;
    const int rr = e >> 6, kk = e & 63;
    short8 v = *(const short8*)(&tile[rr][kk]);
    *(short8*)(outp + (size_t)(d0 + rr) * 2048 + s0 + kk) = v;
  }
}

// ---------------------------------------------------------------- launcher
extern "C" void kernel_launch(void* const* d_in, const int* in_sizes, int n_in,
                              void* d_out, int out_size, void* d_ws, size_t ws_size,
                              hipStream_t stream) {
  const float* h    = (const float*)d_in[0];
  const float* mask = (const float*)d_in[1];
  const float* rn1w = (const float*)d_in[2];
  const float* wq   = (const float*)d_in[3];
  const float* wk   = (const float*)d_in[4];
  const float* wv   = (const float*)d_in[5];
  const float* wo   = (const float*)d_in[6];
  const float* rn2w = (const float*)d_in[7];
  const float* w1   = (const float*)d_in[8];
  const float* fc1w = (const float*)d_in[9];
  const float* fc1b = (const float*)d_in[10];
  const float* fc2w = (const float*)d_in[11];
  const float* fc2b = (const float*)d_in[12];
  const float* w3   = (const float*)d_in[13];

  char* ws = (char*)d_ws;
  size_t off = 0;
  auto alloc = [&](size_t bytes) { char* p = ws + off; off += (bytes + 255) & ~(size_t)255; return p; };
  unsigned short* bufA = (unsigned short*)alloc(16777216);
  unsigned short* bufB = (unsigned short*)alloc(16777216);
  unsigned short* qkv  = (unsigned short*)alloc(50331648);
  float*          r1f  = (float*)alloc(33554432);
  unsigned short* xbuf = (unsigned short*)alloc(67108864);
  unsigned short* g1   = (unsigned short*)alloc(33554432);
  unsigned short* wt   = (unsigned short*)alloc(67108864);
  if (off > ws_size) return;

  // attention path
  rmsnorm_k<<<4096, 256, 0, stream>>>(h, rn1w, bufA);
  transpose2d<<<dim3(32, 32), 256, 0, stream>>>(wq, wt,                 2048, 2048);
  transpose2d<<<dim3(32, 32), 256, 0, stream>>>(wk, wt + 2048 * 2048,   2048, 2048);
  transpose2d<<<dim3(32, 32), 256, 0, stream>>>(wv, wt + 2 * 2048 * 2048, 2048, 2048);
  gemm_bt256<EPI_BF16><<<384, 512, 0, stream>>>(bufA, wt, qkv, nullptr, nullptr, 4096, 6144, 2048, 8, 6);
  transpose_v<<<dim3(32, 2, 32), 256, 0, stream>>>(qkv, bufB);
  attn_fwd<<<dim3(32, 16, 2), 256, 0, stream>>>(qkv, bufB, mask, bufA);
  transpose2d<<<dim3(32, 32), 256, 0, stream>>>(wo, wt, 2048, 2048);
  gemm_bt<EPI_RESID_F32><<<512, 256, 0, stream>>>(bufA, wt, r1f, h, 4096, 2048, 2048, 8, 8);

  // FFN path
  rmsnorm_k<<<4096, 256, 0, stream>>>(r1f, rn2w, bufB);
  transpose2d<<<dim3(128, 32), 256, 0, stream>>>(w1, wt, 2048, 8192);
  gemm_bt256<EPI_BF16><<<512, 512, 0, stream>>>(bufB, wt, xbuf, nullptr, nullptr, 4096, 8192, 2048, 8, 8);
  transpose2d<<<dim3(64, 128), 256, 0, stream>>>(fc1w, wt, 8192, 4096);
  gemm_bt256<EPI_BIAS_BF16><<<256, 512, 0, stream>>>(xbuf, wt, g1, fc1b, nullptr, 4096, 4096, 8192, 4, 8);
  transpose2d<<<dim3(64, 128), 256, 0, stream>>>(fc2w, wt, 8192, 4096);
  unsigned short* gated = qkv;
  gemm_bt256<EPI_SWIGLU><<<256, 512, 0, stream>>>(xbuf, wt, gated, fc2b, g1, 4096, 4096, 8192, 4, 8);
  transpose2d<<<dim3(32, 64), 256, 0, stream>>>(w3, wt, 4096, 2048);
  gemm_bt<EPI_RESID_OUT><<<512, 256, 0, stream>>>(gated, wt, d_out, r1f, 4096, 2048, 4096, 8, 8);
}

// Round 11
// 1159.101 us; speedup vs baseline: 1.1790x; 1.1790x over previous
//
#include <hip/hip_runtime.h>
#include <hip/hip_bf16.h>
#include <stdint.h>

using short8 = __attribute__((ext_vector_type(8))) short;
using uint4v = __attribute__((ext_vector_type(4))) unsigned int;
using f32x4  = __attribute__((ext_vector_type(4))) float;

#define DEV __device__ __forceinline__

DEV float b2f(unsigned short u) {
  union { unsigned int i; float f; } v; v.i = ((unsigned int)u) << 16; return v.f;
}
DEV unsigned short f2b(float f) {
  union { float f; unsigned int i; } v; v.f = f;
  unsigned int x = v.i;
  return (unsigned short)((x + 0x7FFFu + ((x >> 16) & 1u)) >> 16);
}
DEV void g2lds16(const void* g, void* l) {
  __builtin_amdgcn_global_load_lds((const __attribute__((address_space(1))) void*)g,
                                   (__attribute__((address_space(3))) void*)l, 16, 0, 0);
}

// XCD-rectangular block mapping: XCD (wg&7) owns an rby x rbx rectangle of (by,bx).
DEV void xcd_rect_map(int wg, int nbx, int rby, int rbx, int& by, int& bx) {
  const int xcd_cols = nbx / rbx;
  const int xcd = wg & 7, local = wg >> 3;
  const int xr = xcd / xcd_cols, xc = xcd % xcd_cols;
  by = xr * rby + local / rbx;
  bx = xc * rbx + local % rbx;
}

enum { EPI_BF16 = 0, EPI_RESID_F32 = 1, EPI_BIAS_BF16 = 2, EPI_RESID_OUT = 3, EPI_SWIGLU = 4 };

// ---------------------------------------------------------------- GEMM 256x256, 16x16x32, free-running,
// counted-vmcnt staging with 3-deep B buffer (LDS = 64KB A + 96KB B = 160KB).
// Staging per tile t: A(t+1) at p0 (into As[(t+1)&1]), B(t+2) at p1 (into Bs[(t+2)%3]).
// Boundary: vmcnt(4) (allows only B(t+2) in flight; A(t+1) forced; B(t+1) proven landed
// by the PREVIOUS boundary's vmcnt(4)) + s_barrier. vmcnt(0) on the last two boundaries.
// Slot-collision audit (free-running, slip bounded by boundary barrier):
//   A(t+1)->As[(t+1)&1]: tile t reads As[t&1]  -> disjoint.
//   B(t+2)->Bs[(t+2)%3]: tile t reads Bs[t%3], t+1 reads Bs[(t+1)%3] -> disjoint.
//   After barrier all waves are past tile t, so staging A(t+2)/B(t+3) into t-era slots is safe.
template<int EPI>
__global__ __launch_bounds__(512, 2)
void gemm_bt256(const unsigned short* __restrict__ A, const unsigned short* __restrict__ Bt,
                void* __restrict__ Cout, const void* __restrict__ extra,
                const void* __restrict__ extra2, int M, int N, int K, int rby, int rbx) {
  __shared__ __align__(16) unsigned short As[2][256 * 64];
  __shared__ __align__(16) unsigned short Bs3[3][256 * 64];
  int by, bx;
  xcd_rect_map(blockIdx.x, N >> 8, rby, rbx, by, bx);
  const int m0 = by << 8, n0 = bx << 8;
  const int t = threadIdx.x;
  const int l = t & 63, wid = t >> 6;
  const int lr = l & 15, lg = l >> 4;
  const int wr = (wid >> 2) << 7;   // 0 or 128
  const int wc = (wid & 3) << 6;    // 0,64,128,192

  f32x4 acc[8][4];
#pragma unroll
  for (int i = 0; i < 8; ++i)
#pragma unroll
    for (int j = 0; j < 4; ++j) acc[i][j] = (f32x4){0.f, 0.f, 0.f, 0.f};

  const int sr = t >> 3;                               // 0..63
  const int scSwz = ((t & 7) << 3) ^ ((sr & 7) << 3);  // pre-swizzled source column
  const unsigned short* Ag = A  + (size_t)(m0 + sr) * K + scSwz;
  const unsigned short* Bg = Bt + (size_t)(n0 + sr) * K + scSwz;
  const int nT = K >> 6;

  const unsigned short* AgNext = Ag + 64;    // source for A(t+1)
  const unsigned short* BgNext2 = Bg + 128;  // source for B(t+2)
  const size_t rowK64 = (size_t)64 * K;

  const int xorv = (lr & 7) << 3;
  const int cb0 = (lg * 8) ^ xorv;
  const int cb1 = (32 + lg * 8) ^ xorv;

  short8 afA[2][2], afB[2][2], bfr[4][2];

#define STAGE_A(buf)                                                  \
  {                                                                   \
    unsigned short* dst = &As[buf][t * 8];                            \
    _Pragma("unroll")                                                 \
    for (int ld = 0; ld < 4; ++ld)                                    \
      g2lds16(AgNext + (size_t)ld * rowK64, dst + ld * 4096);         \
  }
#define STAGE_B2(slot)                                                \
  {                                                                   \
    unsigned short* dst = &Bs3[slot][t * 8];                          \
    _Pragma("unroll")                                                 \
    for (int ld = 0; ld < 4; ++ld)                                    \
      g2lds16(BgNext2 + (size_t)ld * rowK64, dst + ld * 4096);        \
  }
#define READ_A(dst, base, p)                                          \
  {                                                                   \
    const int ro0 = (wr + ((p) * 2 + 0) * 16 + lr) << 6;              \
    const int ro1 = (wr + ((p) * 2 + 1) * 16 + lr) << 6;              \
    dst[0][0] = *(const short8*)((base) + ro0 + cb0);                 \
    dst[0][1] = *(const short8*)((base) + ro0 + cb1);                 \
    dst[1][0] = *(const short8*)((base) + ro1 + cb0);                 \
    dst[1][1] = *(const short8*)((base) + ro1 + cb1);                 \
  }
#define READ_B(base)                                                  \
  {                                                                   \
    _Pragma("unroll")                                                 \
    for (int ni = 0; ni < 4; ++ni) {                                  \
      const int ro = (wc + ni * 16 + lr) << 6;                        \
      bfr[ni][0] = *(const short8*)((base) + ro + cb0);               \
      bfr[ni][1] = *(const short8*)((base) + ro + cb1);               \
    }                                                                 \
  }
#define MFMA_PH(af, r0)                                               \
  {                                                                   \
    _Pragma("unroll")                                                 \
    for (int kk = 0; kk < 2; ++kk)                                    \
      _Pragma("unroll")                                               \
      for (int a = 0; a < 2; ++a)                                     \
        _Pragma("unroll")                                             \
        for (int ni = 0; ni < 4; ++ni)                                \
          acc[(r0) + a][ni] = __builtin_amdgcn_mfma_f32_16x16x32_bf16(\
              af[a][kk], bfr[ni][kk], acc[(r0) + a][ni], 0, 0, 0);    \
  }

  // prologue: stage A(0),B(0); then B(1); force A(0),B(0) with vmcnt(4) (B(1) in flight)
  {
    unsigned short* dstA = &As[0][t * 8];
    unsigned short* dstB = &Bs3[0][t * 8];
#pragma unroll
    for (int ld = 0; ld < 4; ++ld) {
      g2lds16(Ag + (size_t)ld * rowK64, dstA + ld * 4096);
      g2lds16(Bg + (size_t)ld * rowK64, dstB + ld * 4096);
    }
  }
  if (nT > 1) {
    unsigned short* dstB1 = &Bs3[1][t * 8];
    const unsigned short* srcB1 = Bg + 64;
#pragma unroll
    for (int ld = 0; ld < 4; ++ld) g2lds16(srcB1 + (size_t)ld * rowK64, dstB1 + ld * 4096);
    asm volatile("s_waitcnt vmcnt(4)\n\ts_barrier" ::: "memory");
  } else {
    asm volatile("s_waitcnt vmcnt(0)\n\ts_barrier" ::: "memory");
  }

  int bcur = 0;   // Bs slot for current tile
  int bs2 = 2;    // Bs slot for tile t+2 staging
  READ_A(afA, &As[0][0], 0);
  READ_B(&Bs3[0][0]);

  for (int tt = 0; tt < nT; ++tt) {
    const unsigned short* baseA = &As[tt & 1][0];
    const bool more1 = (tt + 1) < nT;
    const bool more2 = (tt + 2) < nT;
    // p0: uses afA; prefetch p1 frags; stage A(t+1)
    READ_A(afB, baseA, 1);
    if (more1) STAGE_A((tt + 1) & 1);
    asm volatile("s_waitcnt lgkmcnt(4)" ::: "memory");
    __builtin_amdgcn_sched_barrier(0);
    __builtin_amdgcn_s_setprio(1);
    MFMA_PH(afA, 0);
    __builtin_amdgcn_s_setprio(0);
    // p1: uses afB; prefetch p2; stage B(t+2)
    READ_A(afA, baseA, 2);
    if (more2) STAGE_B2(bs2);
    asm volatile("s_waitcnt lgkmcnt(4)" ::: "memory");
    __builtin_amdgcn_sched_barrier(0);
    __builtin_amdgcn_s_setprio(1);
    MFMA_PH(afB, 2);
    __builtin_amdgcn_s_setprio(0);
    // p2: uses afA; prefetch p3
    READ_A(afB, baseA, 3);
    asm volatile("s_waitcnt lgkmcnt(4)" ::: "memory");
    __builtin_amdgcn_sched_barrier(0);
    __builtin_amdgcn_s_setprio(1);
    MFMA_PH(afA, 4);
    __builtin_amdgcn_s_setprio(0);
    // p3: uses afB; drain own ds_reads, MFMA, boundary
    asm volatile("s_waitcnt lgkmcnt(0)" ::: "memory");
    __builtin_amdgcn_sched_barrier(0);
    __builtin_amdgcn_s_setprio(1);
    MFMA_PH(afB, 6);
    __builtin_amdgcn_s_setprio(0);
    if (more1) {
      if (more2) asm volatile("s_waitcnt vmcnt(4)" ::: "memory");
      else       asm volatile("s_waitcnt vmcnt(0)" ::: "memory");
      asm volatile("s_barrier" ::: "memory");
      AgNext += 64;
      BgNext2 += 64;
      bcur = (bcur == 2) ? 0 : bcur + 1;
      bs2  = (bs2 == 2) ? 0 : bs2 + 1;
      READ_A(afA, &As[(tt + 1) & 1][0], 0);
      READ_B(&Bs3[bcur][0]);
    }
  }
#undef STAGE_A
#undef STAGE_B2
#undef READ_A
#undef READ_B
#undef MFMA_PH

#pragma unroll
  for (int mi = 0; mi < 8; ++mi) {
#pragma unroll
    for (int ni = 0; ni < 4; ++ni) {
      const int col = n0 + wc + ni * 16 + lr;
#pragma unroll
      for (int j = 0; j < 4; ++j) {
        const int row = m0 + wr + mi * 16 + lg * 4 + j;
        const size_t idx = (size_t)row * N + col;
        const float v = acc[mi][ni][j];
        if constexpr (EPI == EPI_BF16) {
          ((unsigned short*)Cout)[idx] = f2b(v);
        } else if constexpr (EPI == EPI_RESID_F32) {
          ((float*)Cout)[idx] = v + ((const float*)extra)[idx];
        } else if constexpr (EPI == EPI_BIAS_BF16) {
          ((unsigned short*)Cout)[idx] = f2b(v + ((const float*)extra)[col]);
        } else if constexpr (EPI == EPI_SWIGLU) {
          const float g1v = b2f(((const unsigned short*)extra2)[idx]);
          const float v2 = v + ((const float*)extra)[col];
          ((unsigned short*)Cout)[idx] = f2b(g1v / (1.f + __expf(-g1v)) * v2);
        } else {
          ((float*)Cout)[idx] = v + ((const float*)extra)[idx];
        }
      }
    }
  }
}

// ---------------------------------------------------------------- GEMM 128x128 (m97 + T2 swizzle) for N=2048 GEMMs
template<int EPI>
__global__ __launch_bounds__(256)
void gemm_bt(const unsigned short* __restrict__ A, const unsigned short* __restrict__ Bt,
             void* __restrict__ Cout, const void* __restrict__ extra,
             int M, int N, int K, int rby, int rbx) {
  __shared__ __align__(16) unsigned short As[128 * 64];
  __shared__ __align__(16) unsigned short Bs[128 * 64];
  int by, bx;
  xcd_rect_map(blockIdx.x, N >> 7, rby, rbx, by, bx);
  const int m0 = by << 7, n0 = bx << 7;
  const int t = threadIdx.x;
  const int l = t & 63, w = t >> 6;
  const int lr = l & 15, lg = l >> 4;
  const int wr = (w >> 1) << 6, wc = (w & 1) << 6;

  f32x4 acc[4][4];
#pragma unroll
  for (int i = 0; i < 4; ++i)
#pragma unroll
    for (int j = 0; j < 4; ++j) acc[i][j] = (f32x4){0.f, 0.f, 0.f, 0.f};

  const int sr = t >> 3;
  const int skSwz = ((t & 7) << 3) ^ ((sr & 7) << 3);
  const unsigned short* Ag = A  + (size_t)(m0 + sr) * K + skSwz;
  const unsigned short* Bg = Bt + (size_t)(n0 + sr) * K + skSwz;
  unsigned short* Al = As + t * 8;
  unsigned short* Bl = Bs + t * 8;

  for (int kt = 0; kt < K; kt += 64) {
#pragma unroll
    for (int c = 0; c < 4; ++c) {
      g2lds16(Ag + (size_t)(c * 32) * K + kt, Al + c * 2048);
      g2lds16(Bg + (size_t)(c * 32) * K + kt, Bl + c * 2048);
    }
    __syncthreads();
#pragma unroll
    for (int ks = 0; ks < 2; ++ks) {
      short8 af[4], bfr[4];
#pragma unroll
      for (int mi = 0; mi < 4; ++mi) {
        const int row = wr + mi * 16 + lr;
        af[mi] = *(const short8*)(As + (row << 6) + (((ks * 32 + lg * 8)) ^ ((row & 7) << 3)));
      }
#pragma unroll
      for (int ni = 0; ni < 4; ++ni) {
        const int row = wc + ni * 16 + lr;
        bfr[ni] = *(const short8*)(Bs + (row << 6) + (((ks * 32 + lg * 8)) ^ ((row & 7) << 3)));
      }
#pragma unroll
      for (int mi = 0; mi < 4; ++mi)
#pragma unroll
        for (int ni = 0; ni < 4; ++ni)
          acc[mi][ni] = __builtin_amdgcn_mfma_f32_16x16x32_bf16(af[mi], bfr[ni], acc[mi][ni], 0, 0, 0);
    }
    __syncthreads();
  }

#pragma unroll
  for (int mi = 0; mi < 4; ++mi) {
#pragma unroll
    for (int ni = 0; ni < 4; ++ni) {
      const int col = n0 + wc + ni * 16 + lr;
#pragma unroll
      for (int j = 0; j < 4; ++j) {
        const int row = m0 + wr + mi * 16 + lg * 4 + j;
        const size_t idx = (size_t)row * N + col;
        const float v = acc[mi][ni][j];
        if constexpr (EPI == EPI_BF16) {
          ((unsigned short*)Cout)[idx] = f2b(v);
        } else if constexpr (EPI == EPI_RESID_F32) {
          ((float*)Cout)[idx] = v + ((const float*)extra)[idx];
        } else if constexpr (EPI == EPI_BIAS_BF16) {
          ((unsigned short*)Cout)[idx] = f2b(v + ((const float*)extra)[col]);
        } else {
          ((float*)Cout)[idx] = v + ((const float*)extra)[idx];
        }
      }
    }
  }
}

// ---------------------------------------------------------------- flash attention
__global__ __launch_bounds__(256)
void attn_fwd(const unsigned short* __restrict__ qkv, const unsigned short* __restrict__ vt,
              const float* __restrict__ mask, unsigned short* __restrict__ out) {
  __shared__ __align__(16) unsigned short Ks[64 * 128];
  __shared__ __align__(16) unsigned short Vs[128 * 64];
  __shared__ __align__(16) unsigned short Ps[4][16 * 64];
  const int b = blockIdx.z, hh = blockIdx.y;
  const int q0 = blockIdx.x << 6;
  const int t = threadIdx.x, l = t & 63, w = t >> 6;
  const int lr = l & 15, lg = l >> 4;
  const float scale = 0.08838834764831845f;

  short8 qf[4];
  {
    const unsigned short* qb = qkv + (size_t)(b * 2048 + q0 + w * 16 + lr) * 6144 + hh * 128;
#pragma unroll
    for (int ks = 0; ks < 4; ++ks) qf[ks] = *(const short8*)(qb + ks * 32 + lg * 8);
  }
  f32x4 acc_o[8];
#pragma unroll
  for (int i = 0; i < 8; ++i) acc_o[i] = (f32x4){0.f, 0.f, 0.f, 0.f};
  float m_r[4], l_r[4];
#pragma unroll
  for (int j = 0; j < 4; ++j) { m_r[j] = -1e30f; l_r[j] = 0.f; }

  const unsigned short* kb = qkv + (size_t)(b * 2048) * 6144 + 2048 + hh * 128;
  const unsigned short* vb = vt + (size_t)(b * 16 + hh) * 128 * 2048;
  const float* mb = mask + b * 2048;

  for (int kt = 0; kt < 2048; kt += 64) {
#pragma unroll
    for (int c = 0; c < 4; ++c) {
      const int e = (c * 256 + t) * 8;
      const int kr = e >> 7, kc = e & 127;
      g2lds16(kb + (size_t)(kt + kr) * 6144 + (kc ^ ((kr & 7) << 3)), Ks + e);
      const int vr = e >> 6, vc = e & 63;
      g2lds16(vb + (size_t)vr * 2048 + kt + (vc ^ ((vr & 7) << 3)), Vs + e);
    }
    __syncthreads();

    f32x4 sc[4];
#pragma unroll
    for (int nt = 0; nt < 4; ++nt) {
      f32x4 s = (f32x4){0.f, 0.f, 0.f, 0.f};
#pragma unroll
      for (int ks = 0; ks < 4; ++ks) {
        short8 kf = *(const short8*)(Ks + ((nt * 16 + lr) << 7) + ((ks * 32 + lg * 8) ^ ((lr & 7) << 3)));
        s = __builtin_amdgcn_mfma_f32_16x16x32_bf16(qf[ks], kf, s, 0, 0, 0);
      }
      sc[nt] = s;
    }
#pragma unroll
    for (int nt = 0; nt < 4; ++nt) {
      const float mv = mb[kt + nt * 16 + lr];
#pragma unroll
      for (int j = 0; j < 4; ++j) sc[nt][j] = sc[nt][j] * scale + mv;
    }
#pragma unroll
    for (int j = 0; j < 4; ++j) {
      float tm = fmaxf(fmaxf(sc[0][j], sc[1][j]), fmaxf(sc[2][j], sc[3][j]));
      tm = fmaxf(tm, __shfl_xor(tm, 1));
      tm = fmaxf(tm, __shfl_xor(tm, 2));
      tm = fmaxf(tm, __shfl_xor(tm, 4));
      tm = fmaxf(tm, __shfl_xor(tm, 8));
      const float mn = fmaxf(m_r[j], tm);
      const float corr = __expf(m_r[j] - mn);
      m_r[j] = mn;
      float ps = 0.f;
#pragma unroll
      for (int nt = 0; nt < 4; ++nt) {
        const float p = __expf(sc[nt][j] - mn);
        sc[nt][j] = p;
        ps += p;
      }
      ps += __shfl_xor(ps, 1);
      ps += __shfl_xor(ps, 2);
      ps += __shfl_xor(ps, 4);
      ps += __shfl_xor(ps, 8);
      l_r[j] = l_r[j] * corr + ps;
#pragma unroll
      for (int di = 0; di < 8; ++di) acc_o[di][j] *= corr;
    }
#pragma unroll
    for (int nt = 0; nt < 4; ++nt)
#pragma unroll
      for (int j = 0; j < 4; ++j) {
        const int q = lg * 4 + j;
        Ps[w][(q << 6) + ((nt * 16 + lr) ^ ((q & 7) << 3))] = f2b(sc[nt][j]);
      }
    asm volatile("s_waitcnt lgkmcnt(0)" ::: "memory");
#pragma unroll
    for (int ks2 = 0; ks2 < 2; ++ks2) {
      short8 pf = *(const short8*)(&Ps[w][(lr << 6) + ((ks2 * 32 + lg * 8) ^ ((lr & 7) << 3))]);
#pragma unroll
      for (int di = 0; di < 8; ++di) {
        short8 vf = *(const short8*)(Vs + ((di * 16 + lr) << 6) + ((ks2 * 32 + lg * 8) ^ ((lr & 7) << 3)));
        acc_o[di] = __builtin_amdgcn_mfma_f32_16x16x32_bf16(pf, vf, acc_o[di], 0, 0, 0);
      }
    }
    __syncthreads();
  }
#pragma unroll
  for (int di = 0; di < 8; ++di)
#pragma unroll
    for (int j = 0; j < 4; ++j) {
      const int q = q0 + w * 16 + lg * 4 + j;
      out[(size_t)(b * 2048 + q) * 2048 + hh * 128 + di * 16 + lr] = f2b(acc_o[di][j] / l_r[j]);
    }
}

// ---------------------------------------------------------------- RMSNorm (fp32 in, bf16 out, D=2048)
__global__ __launch_bounds__(256)
void rmsnorm_k(const float* __restrict__ in, const float* __restrict__ wgt,
               unsigned short* __restrict__ out) {
  __shared__ float red[4];
  const int row = blockIdx.x, t = threadIdx.x;
  const float4* rp = (const float4*)(in + (size_t)row * 2048 + t * 8);
  float4 a = rp[0], b = rp[1];
  float x[8] = {a.x, a.y, a.z, a.w, b.x, b.y, b.z, b.w};
  float s = 0.f;
#pragma unroll
  for (int i = 0; i < 8; ++i) s += x[i] * x[i];
#pragma unroll
  for (int m = 1; m < 64; m <<= 1) s += __shfl_xor(s, m);
  const int l = t & 63, w = t >> 6;
  if (l == 0) red[w] = s;
  __syncthreads();
  const float tot = red[0] + red[1] + red[2] + red[3];
  const float rr = rsqrtf(tot * (1.f / 2048.f) + 1e-5f);
  const float4* wp = (const float4*)(wgt + t * 8);
  float4 wa = wp[0], wb = wp[1];
  float ww[8] = {wa.x, wa.y, wa.z, wa.w, wb.x, wb.y, wb.z, wb.w};
  short8 o;
#pragma unroll
  for (int i = 0; i < 8; ++i) o[i] = (short)f2b(x[i] * rr * ww[i]);
  *(short8*)(out + (size_t)row * 2048 + t * 8) = o;
}

// ---------------------------------------------------------------- transpose + fp32->bf16 (pair-packed LDS)
__global__ __launch_bounds__(256)
void transpose2d(const float* __restrict__ in, unsigned short* __restrict__ out,
                 int R, int C) {
  __shared__ __align__(16) unsigned int tile2[64][36];
  const int r0 = blockIdx.y << 6, c0 = blockIdx.x << 6;
  const int t = threadIdx.x;
#pragma unroll
  for (int it = 0; it < 2; ++it) {
    const int p = it * 256 + t;
    const int r2 = p >> 4;
    const int c = (p & 15) << 2;
    const float* src = in + (size_t)(r0 + r2 * 2) * C + c0 + c;
    float4 va = *(const float4*)(src);
    float4 vb = *(const float4*)(src + C);
    tile2[c + 0][r2] = (unsigned int)f2b(va.x) | ((unsigned int)f2b(vb.x) << 16);
    tile2[c + 1][r2] = (unsigned int)f2b(va.y) | ((unsigned int)f2b(vb.y) << 16);
    tile2[c + 2][r2] = (unsigned int)f2b(va.z) | ((unsigned int)f2b(vb.z) << 16);
    tile2[c + 3][r2] = (unsigned int)f2b(va.w) | ((unsigned int)f2b(vb.w) << 16);
  }
  __syncthreads();
#pragma unroll
  for (int it = 0; it < 2; ++it) {
    const int u = it * 256 + t;
    const int rr = u >> 3;
    const int k8 = u & 7;
    uint4v v = *(const uint4v*)(&tile2[rr][k8 * 4]);
    short8 o;
#pragma unroll
    for (int j = 0; j < 4; ++j) {
      o[2 * j]     = (short)(v[j] & 0xFFFFu);
      o[2 * j + 1] = (short)(v[j] >> 16);
    }
    *(short8*)(out + (size_t)(c0 + rr) * R + r0 + k8 * 8) = o;
  }
}

// ---------------------------------------------------------------- V transpose
__global__ __launch_bounds__(256)
void transpose_v(const unsigned short* __restrict__ qkv, unsigned short* __restrict__ vt) {
  __shared__ __align__(16) unsigned short tile[64][72];
  const int s0 = blockIdx.x << 6, d0 = blockIdx.y << 6;
  const int z = blockIdx.z;
  const unsigned short* in = qkv + (size_t)((z >> 4) * 2048) * 6144 + 4096 + (z & 15) * 128;
  unsigned short* outp = vt + (size_t)z * 128 * 2048;
  const int t = threadIdx.x;
#pragma unroll
  for (int it = 0; it < 2; ++it) {
    const int e = (it * 256 + t) * 8;
    const int r = e >> 6, cc = e & 63;
    short8 v = *(const short8*)(in + (size_t)(s0 + r) * 6144 + d0 + cc);
#pragma unroll
    for (int i = 0; i < 8; ++i) tile[cc + i][r] = (unsigned short)v[i];
  }
  __syncthreads();
#pragma unroll
  for (int it = 0; it < 2; ++it) {
    const int e = (it * 256 + t) * 8;
    const int rr = e >> 6, kk = e & 63;
    short8 v = *(const short8*)(&tile[rr][kk]);
    *(short8*)(outp + (size_t)(d0 + rr) * 2048 + s0 + kk) = v;
  }
}

// ---------------------------------------------------------------- launcher
extern "C" void kernel_launch(void* const* d_in, const int* in_sizes, int n_in,
                              void* d_out, int out_size, void* d_ws, size_t ws_size,
                              hipStream_t stream) {
  const float* h    = (const float*)d_in[0];
  const float* mask = (const float*)d_in[1];
  const float* rn1w = (const float*)d_in[2];
  const float* wq   = (const float*)d_in[3];
  const float* wk   = (const float*)d_in[4];
  const float* wv   = (const float*)d_in[5];
  const float* wo   = (const float*)d_in[6];
  const float* rn2w = (const float*)d_in[7];
  const float* w1   = (const float*)d_in[8];
  const float* fc1w = (const float*)d_in[9];
  const float* fc1b = (const float*)d_in[10];
  const float* fc2w = (const float*)d_in[11];
  const float* fc2b = (const float*)d_in[12];
  const float* w3   = (const float*)d_in[13];

  char* ws = (char*)d_ws;
  size_t off = 0;
  auto alloc = [&](size_t bytes) { char* p = ws + off; off += (bytes + 255) & ~(size_t)255; return p; };
  unsigned short* bufA = (unsigned short*)alloc(16777216);
  unsigned short* bufB = (unsigned short*)alloc(16777216);
  unsigned short* qkv  = (unsigned short*)alloc(50331648);
  float*          r1f  = (float*)alloc(33554432);
  unsigned short* xbuf = (unsigned short*)alloc(67108864);
  unsigned short* g1   = (unsigned short*)alloc(33554432);
  unsigned short* wt   = (unsigned short*)alloc(67108864);
  if (off > ws_size) return;

  // attention path
  rmsnorm_k<<<4096, 256, 0, stream>>>(h, rn1w, bufA);
  transpose2d<<<dim3(32, 32), 256, 0, stream>>>(wq, wt,                 2048, 2048);
  transpose2d<<<dim3(32, 32), 256, 0, stream>>>(wk, wt + 2048 * 2048,   2048, 2048);
  transpose2d<<<dim3(32, 32), 256, 0, stream>>>(wv, wt + 2 * 2048 * 2048, 2048, 2048);
  gemm_bt256<EPI_BF16><<<384, 512, 0, stream>>>(bufA, wt, qkv, nullptr, nullptr, 4096, 6144, 2048, 8, 6);
  transpose_v<<<dim3(32, 2, 32), 256, 0, stream>>>(qkv, bufB);
  attn_fwd<<<dim3(32, 16, 2), 256, 0, stream>>>(qkv, bufB, mask, bufA);
  transpose2d<<<dim3(32, 32), 256, 0, stream>>>(wo, wt, 2048, 2048);
  gemm_bt<EPI_RESID_F32><<<512, 256, 0, stream>>>(bufA, wt, r1f, h, 4096, 2048, 2048, 8, 8);

  // FFN path
  rmsnorm_k<<<4096, 256, 0, stream>>>(r1f, rn2w, bufB);
  transpose2d<<<dim3(128, 32), 256, 0, stream>>>(w1, wt, 2048, 8192);
  gemm_bt256<EPI_BF16><<<512, 512, 0, stream>>>(bufB, wt, xbuf, nullptr, nullptr, 4096, 8192, 2048, 8, 8);
  transpose2d<<<dim3(64, 128), 256, 0, stream>>>(fc1w, wt, 8192, 4096);
  gemm_bt256<EPI_BIAS_BF16><<<256, 512, 0, stream>>>(xbuf, wt, g1, fc1b, nullptr, 4096, 4096, 8192, 4, 8);
  transpose2d<<<dim3(64, 128), 256, 0, stream>>>(fc2w, wt, 8192, 4096);
  unsigned short* gated = qkv;
  gemm_bt256<EPI_SWIGLU><<<256, 512, 0, stream>>>(xbuf, wt, gated, fc2b, g1, 4096, 4096, 8192, 4, 8);
  transpose2d<<<dim3(32, 64), 256, 0, stream>>>(w3, wt, 4096, 2048);
  gemm_bt<EPI_RESID_OUT><<<512, 256, 0, stream>>>(gated, wt, d_out, r1f, 4096, 2048, 4096, 8, 8);
}

// Round 12
// 1141.845 us; speedup vs baseline: 1.1968x; 1.0151x over previous
//
#include <hip/hip_runtime.h>
#include <hip/hip_bf16.h>
#include <stdint.h>

using short8 = __attribute__((ext_vector_type(8))) short;
using uint4v = __attribute__((ext_vector_type(4))) unsigned int;
using f32x4  = __attribute__((ext_vector_type(4))) float;

#define DEV __device__ __forceinline__

DEV float b2f(unsigned short u) {
  union { unsigned int i; float f; } v; v.i = ((unsigned int)u) << 16; return v.f;
}
DEV unsigned short f2b(float f) {
  union { float f; unsigned int i; } v; v.f = f;
  unsigned int x = v.i;
  return (unsigned short)((x + 0x7FFFu + ((x >> 16) & 1u)) >> 16);
}
DEV void g2lds16(const void* g, void* l) {
  __builtin_amdgcn_global_load_lds((const __attribute__((address_space(1))) void*)g,
                                   (__attribute__((address_space(3))) void*)l, 16, 0, 0);
}

// XCD-rectangular block mapping
DEV void xcd_rect_map(int wg, int nbx, int rby, int rbx, int& by, int& bx) {
  const int xcd_cols = nbx / rbx;
  const int xcd = wg & 7, local = wg >> 3;
  const int xr = xcd / xcd_cols, xc = xcd % xcd_cols;
  by = xr * rby + local / rbx;
  bx = xc * rbx + local % rbx;
}

enum { EPI_BF16 = 0, EPI_RESID_F32 = 1, EPI_BIAS_BF16 = 2, EPI_RESID_OUT = 3, EPI_SWIGLU = 4 };

// ---------------------------------------------------------------- GEMM 256x256, free-running, 3-deep B,
// B-fragment reads hoisted to p3 (next tile's B read into bfrN under p3's MFMA + boundary).
// Queue invariants per tile t (loads, oldest-first), prior boundary left B(t+1) in flight:
//   p0 stages A(t+1): [B(t+1):4, A(t+1):4]
//   p1 stages B(t+2): [B(t+1):4, A(t+1):4, B(t+2):4]
//   p2: vmcnt(8) -> B(t+1) landed (vmcnt(4) if no B(t+2))
//   p3: READ_B(bfrN) from slot (t+1)%3 (not written during t; writes go to (t+2)%3)
//   boundary: vmcnt(4) -> A(t+1) landed, B(t+2) stays in flight; barrier; READ_A(p0) only.
template<int EPI>
__global__ __launch_bounds__(512, 2)
void gemm_bt256(const unsigned short* __restrict__ A, const unsigned short* __restrict__ Bt,
                void* __restrict__ Cout, const void* __restrict__ extra,
                const void* __restrict__ extra2, int M, int N, int K, int rby, int rbx) {
  __shared__ __align__(16) unsigned short As[2][256 * 64];
  __shared__ __align__(16) unsigned short Bs3[3][256 * 64];
  int by, bx;
  xcd_rect_map(blockIdx.x, N >> 8, rby, rbx, by, bx);
  const int m0 = by << 8, n0 = bx << 8;
  const int t = threadIdx.x;
  const int l = t & 63, wid = t >> 6;
  const int lr = l & 15, lg = l >> 4;
  const int wr = (wid >> 2) << 7;   // 0 or 128
  const int wc = (wid & 3) << 6;    // 0,64,128,192

  f32x4 acc[8][4];
#pragma unroll
  for (int i = 0; i < 8; ++i)
#pragma unroll
    for (int j = 0; j < 4; ++j) acc[i][j] = (f32x4){0.f, 0.f, 0.f, 0.f};

  const int sr = t >> 3;
  const int scSwz = ((t & 7) << 3) ^ ((sr & 7) << 3);
  const unsigned short* Ag = A  + (size_t)(m0 + sr) * K + scSwz;
  const unsigned short* Bg = Bt + (size_t)(n0 + sr) * K + scSwz;
  const int nT = K >> 6;   // always even (K = 2048 or 8192)

  const unsigned short* AgNext = Ag + 64;    // source for A(t+1)
  const unsigned short* BgNext2 = Bg + 128;  // source for B(t+2)
  const size_t rowK64 = (size_t)64 * K;

  const int xorv = (lr & 7) << 3;
  const int cb0 = (lg * 8) ^ xorv;
  const int cb1 = (32 + lg * 8) ^ xorv;

  short8 afA[2][2], afB[2][2], bfrA[4][2], bfrB[4][2];

#define STAGE_A(buf)                                                  \
  {                                                                   \
    unsigned short* dst = &As[buf][t * 8];                            \
    _Pragma("unroll")                                                 \
    for (int ld = 0; ld < 4; ++ld)                                    \
      g2lds16(AgNext + (size_t)ld * rowK64, dst + ld * 4096);         \
  }
#define STAGE_B2(slot)                                                \
  {                                                                   \
    unsigned short* dst = &Bs3[slot][t * 8];                          \
    _Pragma("unroll")                                                 \
    for (int ld = 0; ld < 4; ++ld)                                    \
      g2lds16(BgNext2 + (size_t)ld * rowK64, dst + ld * 4096);        \
  }
#define READ_A(dst, base, p)                                          \
  {                                                                   \
    const int ro0 = (wr + ((p) * 2 + 0) * 16 + lr) << 6;              \
    const int ro1 = (wr + ((p) * 2 + 1) * 16 + lr) << 6;              \
    dst[0][0] = *(const short8*)((base) + ro0 + cb0);                 \
    dst[0][1] = *(const short8*)((base) + ro0 + cb1);                 \
    dst[1][0] = *(const short8*)((base) + ro1 + cb0);                 \
    dst[1][1] = *(const short8*)((base) + ro1 + cb1);                 \
  }
#define READ_B(dst, base)                                             \
  {                                                                   \
    _Pragma("unroll")                                                 \
    for (int ni = 0; ni < 4; ++ni) {                                  \
      const int ro = (wc + ni * 16 + lr) << 6;                        \
      dst[ni][0] = *(const short8*)((base) + ro + cb0);               \
      dst[ni][1] = *(const short8*)((base) + ro + cb1);               \
    }                                                                 \
  }
#define MFMA_PH(af, bfr, r0)                                          \
  {                                                                   \
    _Pragma("unroll")                                                 \
    for (int kk = 0; kk < 2; ++kk)                                    \
      _Pragma("unroll")                                               \
      for (int a = 0; a < 2; ++a)                                     \
        _Pragma("unroll")                                             \
        for (int ni = 0; ni < 4; ++ni)                                \
          acc[(r0) + a][ni] = __builtin_amdgcn_mfma_f32_16x16x32_bf16(\
              af[a][kk], bfr[ni][kk], acc[(r0) + a][ni], 0, 0, 0);    \
  }

#define TILE_BODY(tt, BFR, BFRN)                                      \
  {                                                                   \
    const unsigned short* baseA = &As[(tt) & 1][0];                   \
    const bool more1 = ((tt) + 1) < nT;                               \
    const bool more2 = ((tt) + 2) < nT;                               \
    /* p0: MFMA(afA,BFR); prefetch afB(p1); stage A(t+1) */           \
    READ_A(afB, baseA, 1);                                            \
    if (more1) STAGE_A(((tt) + 1) & 1);                               \
    asm volatile("s_waitcnt lgkmcnt(4)" ::: "memory");                \
    __builtin_amdgcn_sched_barrier(0);                                \
    __builtin_amdgcn_s_setprio(1);                                    \
    MFMA_PH(afA, BFR, 0);                                             \
    __builtin_amdgcn_s_setprio(0);                                    \
    /* p1: MFMA(afB,BFR); prefetch afA(p2); stage B(t+2) */           \
    READ_A(afA, baseA, 2);                                            \
    if (more2) STAGE_B2(bs2);                                         \
    asm volatile("s_waitcnt lgkmcnt(4)" ::: "memory");                \
    __builtin_amdgcn_sched_barrier(0);                                \
    __builtin_amdgcn_s_setprio(1);                                    \
    MFMA_PH(afB, BFR, 2);                                             \
    __builtin_amdgcn_s_setprio(0);                                    \
    /* p2: MFMA(afA,BFR); prefetch afB(p3); ensure B(t+1) landed */   \
    READ_A(afB, baseA, 3);                                            \
    if (more1) {                                                      \
      if (more2) asm volatile("s_waitcnt vmcnt(8)" ::: "memory");     \
      else       asm volatile("s_waitcnt vmcnt(4)" ::: "memory");     \
    }                                                                 \
    asm volatile("s_waitcnt lgkmcnt(4)" ::: "memory");                \
    __builtin_amdgcn_sched_barrier(0);                                \
    __builtin_amdgcn_s_setprio(1);                                    \
    MFMA_PH(afA, BFR, 4);                                             \
    __builtin_amdgcn_s_setprio(0);                                    \
    /* p3: read next tile's B into BFRN, MFMA(afB,BFR) */             \
    if (more1) {                                                      \
      READ_B(BFRN, &Bs3[bnext][0]);                                   \
      asm volatile("s_waitcnt lgkmcnt(8)" ::: "memory");              \
    } else {                                                          \
      asm volatile("s_waitcnt lgkmcnt(0)" ::: "memory");              \
    }                                                                 \
    __builtin_amdgcn_sched_barrier(0);                                \
    __builtin_amdgcn_s_setprio(1);                                    \
    MFMA_PH(afB, BFR, 6);                                             \
    __builtin_amdgcn_s_setprio(0);                                    \
    if (more1) {                                                      \
      if (more2) asm volatile("s_waitcnt vmcnt(4)" ::: "memory");     \
      else       asm volatile("s_waitcnt vmcnt(0)" ::: "memory");     \
      asm volatile("s_barrier" ::: "memory");                         \
      AgNext += 64;                                                   \
      BgNext2 += 64;                                                  \
      bnext = (bnext == 2) ? 0 : bnext + 1;                           \
      bs2  = (bs2 == 2) ? 0 : bs2 + 1;                                \
      READ_A(afA, &As[((tt) + 1) & 1][0], 0);                         \
    }                                                                 \
  }

  // prologue: stage A0,B0,B1 (12 loads); vmcnt(4) -> A0,B0 landed, B1 in flight
  {
    unsigned short* dstA = &As[0][t * 8];
    unsigned short* dstB = &Bs3[0][t * 8];
#pragma unroll
    for (int ld = 0; ld < 4; ++ld) {
      g2lds16(Ag + (size_t)ld * rowK64, dstA + ld * 4096);
      g2lds16(Bg + (size_t)ld * rowK64, dstB + ld * 4096);
    }
  }
  {
    unsigned short* dstB1 = &Bs3[1][t * 8];
    const unsigned short* srcB1 = Bg + 64;
#pragma unroll
    for (int ld = 0; ld < 4; ++ld) g2lds16(srcB1 + (size_t)ld * rowK64, dstB1 + ld * 4096);
  }
  asm volatile("s_waitcnt vmcnt(4)\n\ts_barrier" ::: "memory");

  int bnext = 1;  // Bs slot holding B(t+1)
  int bs2 = 2;    // Bs slot for staging B(t+2)
  READ_A(afA, &As[0][0], 0);
  READ_B(bfrA, &Bs3[0][0]);

  for (int tp = 0; tp < nT; tp += 2) {
    TILE_BODY(tp,     bfrA, bfrB);
    TILE_BODY(tp + 1, bfrB, bfrA);
  }
#undef STAGE_A
#undef STAGE_B2
#undef READ_A
#undef READ_B
#undef MFMA_PH
#undef TILE_BODY

#pragma unroll
  for (int mi = 0; mi < 8; ++mi) {
#pragma unroll
    for (int ni = 0; ni < 4; ++ni) {
      const int col = n0 + wc + ni * 16 + lr;
#pragma unroll
      for (int j = 0; j < 4; ++j) {
        const int row = m0 + wr + mi * 16 + lg * 4 + j;
        const size_t idx = (size_t)row * N + col;
        const float v = acc[mi][ni][j];
        if constexpr (EPI == EPI_BF16) {
          ((unsigned short*)Cout)[idx] = f2b(v);
        } else if constexpr (EPI == EPI_RESID_F32) {
          ((float*)Cout)[idx] = v + ((const float*)extra)[idx];
        } else if constexpr (EPI == EPI_BIAS_BF16) {
          ((unsigned short*)Cout)[idx] = f2b(v + ((const float*)extra)[col]);
        } else if constexpr (EPI == EPI_SWIGLU) {
          const float g1v = b2f(((const unsigned short*)extra2)[idx]);
          const float v2 = v + ((const float*)extra)[col];
          ((unsigned short*)Cout)[idx] = f2b(g1v / (1.f + __expf(-g1v)) * v2);
        } else {
          ((float*)Cout)[idx] = v + ((const float*)extra)[idx];
        }
      }
    }
  }
}

// ---------------------------------------------------------------- GEMM 128x128 (m97 + T2 swizzle) for N=2048 GEMMs
template<int EPI>
__global__ __launch_bounds__(256)
void gemm_bt(const unsigned short* __restrict__ A, const unsigned short* __restrict__ Bt,
             void* __restrict__ Cout, const void* __restrict__ extra,
             int M, int N, int K, int rby, int rbx) {
  __shared__ __align__(16) unsigned short As[128 * 64];
  __shared__ __align__(16) unsigned short Bs[128 * 64];
  int by, bx;
  xcd_rect_map(blockIdx.x, N >> 7, rby, rbx, by, bx);
  const int m0 = by << 7, n0 = bx << 7;
  const int t = threadIdx.x;
  const int l = t & 63, w = t >> 6;
  const int lr = l & 15, lg = l >> 4;
  const int wr = (w >> 1) << 6, wc = (w & 1) << 6;

  f32x4 acc[4][4];
#pragma unroll
  for (int i = 0; i < 4; ++i)
#pragma unroll
    for (int j = 0; j < 4; ++j) acc[i][j] = (f32x4){0.f, 0.f, 0.f, 0.f};

  const int sr = t >> 3;
  const int skSwz = ((t & 7) << 3) ^ ((sr & 7) << 3);
  const unsigned short* Ag = A  + (size_t)(m0 + sr) * K + skSwz;
  const unsigned short* Bg = Bt + (size_t)(n0 + sr) * K + skSwz;
  unsigned short* Al = As + t * 8;
  unsigned short* Bl = Bs + t * 8;

  for (int kt = 0; kt < K; kt += 64) {
#pragma unroll
    for (int c = 0; c < 4; ++c) {
      g2lds16(Ag + (size_t)(c * 32) * K + kt, Al + c * 2048);
      g2lds16(Bg + (size_t)(c * 32) * K + kt, Bl + c * 2048);
    }
    __syncthreads();
#pragma unroll
    for (int ks = 0; ks < 2; ++ks) {
      short8 af[4], bfr[4];
#pragma unroll
      for (int mi = 0; mi < 4; ++mi) {
        const int row = wr + mi * 16 + lr;
        af[mi] = *(const short8*)(As + (row << 6) + (((ks * 32 + lg * 8)) ^ ((row & 7) << 3)));
      }
#pragma unroll
      for (int ni = 0; ni < 4; ++ni) {
        const int row = wc + ni * 16 + lr;
        bfr[ni] = *(const short8*)(Bs + (row << 6) + (((ks * 32 + lg * 8)) ^ ((row & 7) << 3)));
      }
#pragma unroll
      for (int mi = 0; mi < 4; ++mi)
#pragma unroll
        for (int ni = 0; ni < 4; ++ni)
          acc[mi][ni] = __builtin_amdgcn_mfma_f32_16x16x32_bf16(af[mi], bfr[ni], acc[mi][ni], 0, 0, 0);
    }
    __syncthreads();
  }

#pragma unroll
  for (int mi = 0; mi < 4; ++mi) {
#pragma unroll
    for (int ni = 0; ni < 4; ++ni) {
      const int col = n0 + wc + ni * 16 + lr;
#pragma unroll
      for (int j = 0; j < 4; ++j) {
        const int row = m0 + wr + mi * 16 + lg * 4 + j;
        const size_t idx = (size_t)row * N + col;
        const float v = acc[mi][ni][j];
        if constexpr (EPI == EPI_BF16) {
          ((unsigned short*)Cout)[idx] = f2b(v);
        } else if constexpr (EPI == EPI_RESID_F32) {
          ((float*)Cout)[idx] = v + ((const float*)extra)[idx];
        } else if constexpr (EPI == EPI_BIAS_BF16) {
          ((unsigned short*)Cout)[idx] = f2b(v + ((const float*)extra)[col]);
        } else {
          ((float*)Cout)[idx] = v + ((const float*)extra)[idx];
        }
      }
    }
  }
}

// ---------------------------------------------------------------- flash attention
__global__ __launch_bounds__(256)
void attn_fwd(const unsigned short* __restrict__ qkv, const unsigned short* __restrict__ vt,
              const float* __restrict__ mask, unsigned short* __restrict__ out) {
  __shared__ __align__(16) unsigned short Ks[64 * 128];
  __shared__ __align__(16) unsigned short Vs[128 * 64];
  __shared__ __align__(16) unsigned short Ps[4][16 * 64];
  const int b = blockIdx.z, hh = blockIdx.y;
  const int q0 = blockIdx.x << 6;
  const int t = threadIdx.x, l = t & 63, w = t >> 6;
  const int lr = l & 15, lg = l >> 4;
  const float scale = 0.08838834764831845f;

  short8 qf[4];
  {
    const unsigned short* qb = qkv + (size_t)(b * 2048 + q0 + w * 16 + lr) * 6144 + hh * 128;
#pragma unroll
    for (int ks = 0; ks < 4; ++ks) qf[ks] = *(const short8*)(qb + ks * 32 + lg * 8);
  }
  f32x4 acc_o[8];
#pragma unroll
  for (int i = 0; i < 8; ++i) acc_o[i] = (f32x4){0.f, 0.f, 0.f, 0.f};
  float m_r[4], l_r[4];
#pragma unroll
  for (int j = 0; j < 4; ++j) { m_r[j] = -1e30f; l_r[j] = 0.f; }

  const unsigned short* kb = qkv + (size_t)(b * 2048) * 6144 + 2048 + hh * 128;
  const unsigned short* vb = vt + (size_t)(b * 16 + hh) * 128 * 2048;
  const float* mb = mask + b * 2048;

  for (int kt = 0; kt < 2048; kt += 64) {
#pragma unroll
    for (int c = 0; c < 4; ++c) {
      const int e = (c * 256 + t) * 8;
      const int kr = e >> 7, kc = e & 127;
      g2lds16(kb + (size_t)(kt + kr) * 6144 + (kc ^ ((kr & 7) << 3)), Ks + e);
      const int vr = e >> 6, vc = e & 63;
      g2lds16(vb + (size_t)vr * 2048 + kt + (vc ^ ((vr & 7) << 3)), Vs + e);
    }
    __syncthreads();

    f32x4 sc[4];
#pragma unroll
    for (int nt = 0; nt < 4; ++nt) {
      f32x4 s = (f32x4){0.f, 0.f, 0.f, 0.f};
#pragma unroll
      for (int ks = 0; ks < 4; ++ks) {
        short8 kf = *(const short8*)(Ks + ((nt * 16 + lr) << 7) + ((ks * 32 + lg * 8) ^ ((lr & 7) << 3)));
        s = __builtin_amdgcn_mfma_f32_16x16x32_bf16(qf[ks], kf, s, 0, 0, 0);
      }
      sc[nt] = s;
    }
#pragma unroll
    for (int nt = 0; nt < 4; ++nt) {
      const float mv = mb[kt + nt * 16 + lr];
#pragma unroll
      for (int j = 0; j < 4; ++j) sc[nt][j] = sc[nt][j] * scale + mv;
    }
#pragma unroll
    for (int j = 0; j < 4; ++j) {
      float tm = fmaxf(fmaxf(sc[0][j], sc[1][j]), fmaxf(sc[2][j], sc[3][j]));
      tm = fmaxf(tm, __shfl_xor(tm, 1));
      tm = fmaxf(tm, __shfl_xor(tm, 2));
      tm = fmaxf(tm, __shfl_xor(tm, 4));
      tm = fmaxf(tm, __shfl_xor(tm, 8));
      const float mn = fmaxf(m_r[j], tm);
      const float corr = __expf(m_r[j] - mn);
      m_r[j] = mn;
      float ps = 0.f;
#pragma unroll
      for (int nt = 0; nt < 4; ++nt) {
        const float p = __expf(sc[nt][j] - mn);
        sc[nt][j] = p;
        ps += p;
      }
      ps += __shfl_xor(ps, 1);
      ps += __shfl_xor(ps, 2);
      ps += __shfl_xor(ps, 4);
      ps += __shfl_xor(ps, 8);
      l_r[j] = l_r[j] * corr + ps;
#pragma unroll
      for (int di = 0; di < 8; ++di) acc_o[di][j] *= corr;
    }
#pragma unroll
    for (int nt = 0; nt < 4; ++nt)
#pragma unroll
      for (int j = 0; j < 4; ++j) {
        const int q = lg * 4 + j;
        Ps[w][(q << 6) + ((nt * 16 + lr) ^ ((q & 7) << 3))] = f2b(sc[nt][j]);
      }
    asm volatile("s_waitcnt lgkmcnt(0)" ::: "memory");
#pragma unroll
    for (int ks2 = 0; ks2 < 2; ++ks2) {
      short8 pf = *(const short8*)(&Ps[w][(lr << 6) + ((ks2 * 32 + lg * 8) ^ ((lr & 7) << 3))]);
#pragma unroll
      for (int di = 0; di < 8; ++di) {
        short8 vf = *(const short8*)(Vs + ((di * 16 + lr) << 6) + ((ks2 * 32 + lg * 8) ^ ((lr & 7) << 3)));
        acc_o[di] = __builtin_amdgcn_mfma_f32_16x16x32_bf16(pf, vf, acc_o[di], 0, 0, 0);
      }
    }
    __syncthreads();
  }
#pragma unroll
  for (int di = 0; di < 8; ++di)
#pragma unroll
    for (int j = 0; j < 4; ++j) {
      const int q = q0 + w * 16 + lg * 4 + j;
      out[(size_t)(b * 2048 + q) * 2048 + hh * 128 + di * 16 + lr] = f2b(acc_o[di][j] / l_r[j]);
    }
}

// ---------------------------------------------------------------- RMSNorm (fp32 in, bf16 out, D=2048)
__global__ __launch_bounds__(256)
void rmsnorm_k(const float* __restrict__ in, const float* __restrict__ wgt,
               unsigned short* __restrict__ out) {
  __shared__ float red[4];
  const int row = blockIdx.x, t = threadIdx.x;
  const float4* rp = (const float4*)(in + (size_t)row * 2048 + t * 8);
  float4 a = rp[0], b = rp[1];
  float x[8] = {a.x, a.y, a.z, a.w, b.x, b.y, b.z, b.w};
  float s = 0.f;
#pragma unroll
  for (int i = 0; i < 8; ++i) s += x[i] * x[i];
#pragma unroll
  for (int m = 1; m < 64; m <<= 1) s += __shfl_xor(s, m);
  const int l = t & 63, w = t >> 6;
  if (l == 0) red[w] = s;
  __syncthreads();
  const float tot = red[0] + red[1] + red[2] + red[3];
  const float rr = rsqrtf(tot * (1.f / 2048.f) + 1e-5f);
  const float4* wp = (const float4*)(wgt + t * 8);
  float4 wa = wp[0], wb = wp[1];
  float ww[8] = {wa.x, wa.y, wa.z, wa.w, wb.x, wb.y, wb.z, wb.w};
  short8 o;
#pragma unroll
  for (int i = 0; i < 8; ++i) o[i] = (short)f2b(x[i] * rr * ww[i]);
  *(short8*)(out + (size_t)row * 2048 + t * 8) = o;
}

// ---------------------------------------------------------------- transpose + fp32->bf16 (pair-packed LDS)
__global__ __launch_bounds__(256)
void transpose2d(const float* __restrict__ in, unsigned short* __restrict__ out,
                 int R, int C) {
  __shared__ __align__(16) unsigned int tile2[64][36];
  const int r0 = blockIdx.y << 6, c0 = blockIdx.x << 6;
  const int t = threadIdx.x;
#pragma unroll
  for (int it = 0; it < 2; ++it) {
    const int p = it * 256 + t;
    const int r2 = p >> 4;
    const int c = (p & 15) << 2;
    const float* src = in + (size_t)(r0 + r2 * 2) * C + c0 + c;
    float4 va = *(const float4*)(src);
    float4 vb = *(const float4*)(src + C);
    tile2[c + 0][r2] = (unsigned int)f2b(va.x) | ((unsigned int)f2b(vb.x) << 16);
    tile2[c + 1][r2] = (unsigned int)f2b(va.y) | ((unsigned int)f2b(vb.y) << 16);
    tile2[c + 2][r2] = (unsigned int)f2b(va.z) | ((unsigned int)f2b(vb.z) << 16);
    tile2[c + 3][r2] = (unsigned int)f2b(va.w) | ((unsigned int)f2b(vb.w) << 16);
  }
  __syncthreads();
#pragma unroll
  for (int it = 0; it < 2; ++it) {
    const int u = it * 256 + t;
    const int rr = u >> 3;
    const int k8 = u & 7;
    uint4v v = *(const uint4v*)(&tile2[rr][k8 * 4]);
    short8 o;
#pragma unroll
    for (int j = 0; j < 4; ++j) {
      o[2 * j]     = (short)(v[j] & 0xFFFFu);
      o[2 * j + 1] = (short)(v[j] >> 16);
    }
    *(short8*)(out + (size_t)(c0 + rr) * R + r0 + k8 * 8) = o;
  }
}

// ---------------------------------------------------------------- V transpose
__global__ __launch_bounds__(256)
void transpose_v(const unsigned short* __restrict__ qkv, unsigned short* __restrict__ vt) {
  __shared__ __align__(16) unsigned short tile[64][72];
  const int s0 = blockIdx.x << 6, d0 = blockIdx.y << 6;
  const int z = blockIdx.z;
  const unsigned short* in = qkv + (size_t)((z >> 4) * 2048) * 6144 + 4096 + (z & 15) * 128;
  unsigned short* outp = vt + (size_t)z * 128 * 2048;
  const int t = threadIdx.x;
#pragma unroll
  for (int it = 0; it < 2; ++it) {
    const int e = (it * 256 + t) * 8;
    const int r = e >> 6, cc = e & 63;
    short8 v = *(const short8*)(in + (size_t)(s0 + r) * 6144 + d0 + cc);
#pragma unroll
    for (int i = 0; i < 8; ++i) tile[cc + i][r] = (unsigned short)v[i];
  }
  __syncthreads();
#pragma unroll
  for (int it = 0; it < 2; ++it) {
    const int e = (it * 256 + t) * 8;
    const int rr = e >> 6, kk = e & 63;
    short8 v = *(const short8*)(&tile[rr][kk]);
    *(short8*)(outp + (size_t)(d0 + rr) * 2048 + s0 + kk) = v;
  }
}

// ---------------------------------------------------------------- launcher
extern "C" void kernel_launch(void* const* d_in, const int* in_sizes, int n_in,
                              void* d_out, int out_size, void* d_ws, size_t ws_size,
                              hipStream_t stream) {
  const float* h    = (const float*)d_in[0];
  const float* mask = (const float*)d_in[1];
  const float* rn1w = (const float*)d_in[2];
  const float* wq   = (const float*)d_in[3];
  const float* wk   = (const float*)d_in[4];
  const float* wv   = (const float*)d_in[5];
  const float* wo   = (const float*)d_in[6];
  const float* rn2w = (const float*)d_in[7];
  const float* w1   = (const float*)d_in[8];
  const float* fc1w = (const float*)d_in[9];
  const float* fc1b = (const float*)d_in[10];
  const float* fc2w = (const float*)d_in[11];
  const float* fc2b = (const float*)d_in[12];
  const float* w3   = (const float*)d_in[13];

  char* ws = (char*)d_ws;
  size_t off = 0;
  auto alloc = [&](size_t bytes) { char* p = ws + off; off += (bytes + 255) & ~(size_t)255; return p; };
  unsigned short* bufA = (unsigned short*)alloc(16777216);
  unsigned short* bufB = (unsigned short*)alloc(16777216);
  unsigned short* qkv  = (unsigned short*)alloc(50331648);
  float*          r1f  = (float*)alloc(33554432);
  unsigned short* xbuf = (unsigned short*)alloc(67108864);
  unsigned short* g1   = (unsigned short*)alloc(33554432);
  unsigned short* wt   = (unsigned short*)alloc(67108864);
  if (off > ws_size) return;

  // attention path
  rmsnorm_k<<<4096, 256, 0, stream>>>(h, rn1w, bufA);
  transpose2d<<<dim3(32, 32), 256, 0, stream>>>(wq, wt,                 2048, 2048);
  transpose2d<<<dim3(32, 32), 256, 0, stream>>>(wk, wt + 2048 * 2048,   2048, 2048);
  transpose2d<<<dim3(32, 32), 256, 0, stream>>>(wv, wt + 2 * 2048 * 2048, 2048, 2048);
  gemm_bt256<EPI_BF16><<<384, 512, 0, stream>>>(bufA, wt, qkv, nullptr, nullptr, 4096, 6144, 2048, 8, 6);
  transpose_v<<<dim3(32, 2, 32), 256, 0, stream>>>(qkv, bufB);
  attn_fwd<<<dim3(32, 16, 2), 256, 0, stream>>>(qkv, bufB, mask, bufA);
  transpose2d<<<dim3(32, 32), 256, 0, stream>>>(wo, wt, 2048, 2048);
  gemm_bt<EPI_RESID_F32><<<512, 256, 0, stream>>>(bufA, wt, r1f, h, 4096, 2048, 2048, 8, 8);

  // FFN path
  rmsnorm_k<<<4096, 256, 0, stream>>>(r1f, rn2w, bufB);
  transpose2d<<<dim3(128, 32), 256, 0, stream>>>(w1, wt, 2048, 8192);
  gemm_bt256<EPI_BF16><<<512, 512, 0, stream>>>(bufB, wt, xbuf, nullptr, nullptr, 4096, 8192, 2048, 8, 8);
  transpose2d<<<dim3(64, 128), 256, 0, stream>>>(fc1w, wt, 8192, 4096);
  gemm_bt256<EPI_BIAS_BF16><<<256, 512, 0, stream>>>(xbuf, wt, g1, fc1b, nullptr, 4096, 4096, 8192, 4, 8);
  transpose2d<<<dim3(64, 128), 256, 0, stream>>>(fc2w, wt, 8192, 4096);
  unsigned short* gated = qkv;
  gemm_bt256<EPI_SWIGLU><<<256, 512, 0, stream>>>(xbuf, wt, gated, fc2b, g1, 4096, 4096, 8192, 4, 8);
  transpose2d<<<dim3(32, 64), 256, 0, stream>>>(w3, wt, 4096, 2048);
  gemm_bt<EPI_RESID_OUT><<<512, 256, 0, stream>>>(gated, wt, d_out, r1f, 4096, 2048, 4096, 8, 8);
}